// Round 6
// baseline (80.757 us; speedup 1.0000x reference)
//
#include <hip/hip_runtime.h>
#include <hip/hip_bf16.h>

// Problem constants
constexpr int BN = 16384;          // batch
constexpr int DN = 64;             // nodes / input dim
constexpr int HN = 64;             // hidden

typedef __attribute__((ext_vector_type(8))) short short8;   // 8 x bf16
typedef __attribute__((ext_vector_type(4))) float f32x4;    // MFMA accumulator
typedef __attribute__((ext_vector_type(2))) float f32x2;    // packed-math pair

__device__ __forceinline__ unsigned int pk2(float lo, float hi) {
    __hip_bfloat162 h = __float22bfloat162_rn(make_float2(lo, hi));
    return *reinterpret_cast<unsigned int*>(&h);
}

__device__ __forceinline__ short8 cvt8(float4 a, float4 b) {
    union { unsigned int u[4]; short8 s; } r;
    r.u[0] = pk2(a.x, a.y); r.u[1] = pk2(a.z, a.w);
    r.u[2] = pk2(b.x, b.y); r.u[3] = pk2(b.z, b.w);
    return r.s;
}

// VALU cross-lane reduce over each 16-lane row: x += row_ror(x, N). After
// ror 8,4,2,1 every lane holds its 16-lane row sum. Pure VALU, no DS pipe.
#define DPP_ROR_ADD(x, N)                                                     \
    x += __int_as_float(__builtin_amdgcn_update_dpp(                          \
            0, __float_as_int(x), 0x120 + (N), 0xf, 0xf, false))

// ---------------------------------------------------------------------------
// Single fused kernel. Block = (256-row batch tile, 4 nodes); 4 waves x 64
// rows. Staging: W1 fp32 + adj folded + bf16-converted in-register into
// XOR-swizzled LDS (32 KB); W2 into LDS; A-fragments fp32->bf16 in-register.
// j-loop (fully unrolled): LDS-only operands, 32 MFMA per wave per j.
// Epilogue: relu * W2 packed fma, DPP row reduction, LDS transpose, f4 store.
// ---------------------------------------------------------------------------
__global__ __launch_bounds__(256, 3) void mlp_kernel(
    const float* __restrict__ X,               // [B][64] fp32
    const float* __restrict__ adj,             // [D][D] fp32
    const float* __restrict__ W1,              // [D][H][64] fp32
    const float* __restrict__ W2,              // [D][H] fp32
    float* __restrict__ out)                   // [B][D] fp32
{
    const int ng    = blockIdx.x & 15;         // node group (4 nodes) fastest:
    const int btile = blockIdx.x >> 4;         // 16 blocks share one X tile
    const int tid   = threadIdx.x;
    const int wave  = tid >> 6;                // 0..3
    const int lane  = tid & 63;
    const int row16 = lane & 15;               // A/B frag row, C/D column (h)
    const int quad  = lane >> 4;               // A/B k-quad, C/D row-quad (b)

    __shared__ unsigned short ldsW1[4 * HN * DN];  // 32 KB, swizzled
    __shared__ float ldsW2[4 * HN];                // 1 KB
    __shared__ float lds_out[256][4];              // 4 KB

    // ---- Stage W2 ----
    ldsW2[tid] = W2[ng * 256 + tid];

    // ---- Stage W1 (fp32) * adj -> bf16, swizzled. 2048 chunks of 8 floats.
    {
        const float* w1src   = W1 + (size_t)ng * (4 * HN * DN);
        const float* adjbase = adj + (size_t)(ng * 4) * DN;
#pragma unroll
        for (int it = 0; it < 8; ++it) {
            int c  = it * 256 + tid;           // 0..2047
            int flat = c * 8;
            int nl = flat >> 12;               // node_local 0..3
            int h  = (flat >> 6) & 63;
            int d  = flat & 63;                // = (c & 7) * 8
            float4 w0 = *reinterpret_cast<const float4*>(w1src + flat);
            float4 w1v = *reinterpret_cast<const float4*>(w1src + flat + 4);
            float4 a0 = *reinterpret_cast<const float4*>(adjbase + nl * DN + d);
            float4 a1 = *reinterpret_cast<const float4*>(adjbase + nl * DN + d + 4);
            float4 m0 = make_float4(w0.x * a0.x, w0.y * a0.y, w0.z * a0.z, w0.w * a0.w);
            float4 m1 = make_float4(w1v.x * a1.x, w1v.y * a1.y, w1v.z * a1.z, w1v.w * a1.w);
            short8 v = cvt8(m0, m1);
            int c8 = d >> 3;
            int elem = nl * 4096 + h * 64 + ((c8 ^ (h & 7)) << 3);
            *reinterpret_cast<short8*>(&ldsW1[elem]) = v;
        }
    }

    // ---- A fragments: fp32 load + in-register bf16 convert (64 rows/wave) ----
    const int b0 = btile * 256 + wave * 64;
    const float* aBase = X + (size_t)(b0 + row16) * DN + quad * 8;
    short8 afrag[4][2];
#pragma unroll
    for (int mt = 0; mt < 4; ++mt)
#pragma unroll
        for (int kk = 0; kk < 2; ++kk) {
            const float* p = aBase + mt * 16 * DN + kk * 32;
            float4 v0 = *reinterpret_cast<const float4*>(p);
            float4 v1 = *reinterpret_cast<const float4*>(p + 4);
            afrag[mt][kk] = cvt8(v0, v1);
        }

    __syncthreads();

    // ---- j-loop: LDS-only operands, fully unrolled ----
#pragma unroll
    for (int j = 0; j < 4; ++j) {
        float w2v[4];
#pragma unroll
        for (int nt = 0; nt < 4; ++nt)
            w2v[nt] = ldsW2[j * 64 + nt * 16 + row16];

        f32x4 acc[4][4];
#pragma unroll
        for (int mt = 0; mt < 4; ++mt)
#pragma unroll
            for (int nt = 0; nt < 4; ++nt)
                acc[mt][nt] = (f32x4){0.f, 0.f, 0.f, 0.f};

#pragma unroll
        for (int kk = 0; kk < 2; ++kk) {
            short8 bfrag[4];
#pragma unroll
            for (int nt = 0; nt < 4; ++nt) {
                int h = nt * 16 + row16;
                int elem = j * 4096 + h * 64 + (((kk * 4 + quad) ^ (row16 & 7)) << 3);
                bfrag[nt] = *reinterpret_cast<const short8*>(&ldsW1[elem]);
            }
#pragma unroll
            for (int nt = 0; nt < 4; ++nt)
#pragma unroll
                for (int mt = 0; mt < 4; ++mt)
                    acc[mt][nt] = __builtin_amdgcn_mfma_f32_16x16x32_bf16(
                        afrag[mt][kk], bfrag[nt], acc[mt][nt], 0, 0, 0);
        }

        // epilogue: out[b,node] = sum_h relu(H[b,h]) * W2[node,h]
        // C/D layout: h = nt*16 + row16, b = mt*16 + quad*4 + reg
#pragma unroll
        for (int mt = 0; mt < 4; ++mt) {
            f32x2 s01 = (f32x2){0.f, 0.f}, s23 = (f32x2){0.f, 0.f};
#pragma unroll
            for (int nt = 0; nt < 4; ++nt) {
                f32x2 m01 = (f32x2){fmaxf(acc[mt][nt][0], 0.f), fmaxf(acc[mt][nt][1], 0.f)};
                f32x2 m23 = (f32x2){fmaxf(acc[mt][nt][2], 0.f), fmaxf(acc[mt][nt][3], 0.f)};
                s01 += m01 * w2v[nt];     // v_pk_fma_f32
                s23 += m23 * w2v[nt];
            }
            float p[4] = {s01[0], s01[1], s23[0], s23[1]};
#pragma unroll
            for (int r = 0; r < 4; ++r) {
                DPP_ROR_ADD(p[r], 8);
                DPP_ROR_ADD(p[r], 4);
                DPP_ROR_ADD(p[r], 2);
                DPP_ROR_ADD(p[r], 1);
            }
            if (row16 < 4)
                lds_out[wave * 64 + mt * 16 + quad * 4 + row16][j] = p[row16];
        }
    }

    __syncthreads();
    // cooperative store: 256 rows; thread t stores row t's float4
    {
        float4 v = *reinterpret_cast<const float4*>(&lds_out[tid][0]);
        *reinterpret_cast<float4*>(out + (size_t)(btile * 256 + tid) * DN + ng * 4) = v;
    }
}

extern "C" void kernel_launch(void* const* d_in, const int* in_sizes, int n_in,
                              void* d_out, int out_size, void* d_ws, size_t ws_size,
                              hipStream_t stream) {
    const float* X   = (const float*)d_in[0];   // [B, D] fp32
    const float* adj = (const float*)d_in[1];   // [D, D] fp32
    const float* W1  = (const float*)d_in[2];   // [D, H, D] fp32
    const float* W2  = (const float*)d_in[3];   // [D, H] fp32
    float* out = (float*)d_out;                 // [B, D] fp32

    (void)d_ws; (void)ws_size;
    mlp_kernel<<<(BN / 256) * 16, 256, 0, stream>>>(X, adj, W1, W2, out);
}

// Round 7
// 78.992 us; speedup vs baseline: 1.0223x; 1.0223x over previous
//
#include <hip/hip_runtime.h>
#include <hip/hip_bf16.h>

// Problem constants
constexpr int BN = 16384;          // batch
constexpr int DN = 64;             // nodes / input dim
constexpr int HN = 64;             // hidden
constexpr int W1ELEMS = DN * HN * DN;   // 262144
constexpr int WCH = W1ELEMS / 4;        // float4 chunks of W1 (65536)

typedef __attribute__((ext_vector_type(8))) short short8;   // 8 x bf16
typedef __attribute__((ext_vector_type(4))) float f32x4;    // MFMA accumulator
typedef __attribute__((ext_vector_type(2))) float f32x2;    // packed-math pair

__device__ __forceinline__ unsigned short f2bf(float f) {
    __hip_bfloat16 h = __float2bfloat16(f);
    return *reinterpret_cast<unsigned short*>(&h);
}

__device__ __forceinline__ short8 cvt8(float4 a, float4 b) {
    short8 r;
    r[0] = (short)f2bf(a.x); r[1] = (short)f2bf(a.y);
    r[2] = (short)f2bf(a.z); r[3] = (short)f2bf(a.w);
    r[4] = (short)f2bf(b.x); r[5] = (short)f2bf(b.y);
    r[6] = (short)f2bf(b.z); r[7] = (short)f2bf(b.w);
    return r;
}

// VALU cross-lane reduce over each 16-lane row: x += row_ror(x, N). After
// ror 8,4,2,1 every lane holds its 16-lane row sum. Pure VALU, no DS pipe.
#define DPP_ROR_ADD(x, N)                                                     \
    x += __int_as_float(__builtin_amdgcn_update_dpp(                          \
            0, __float_as_int(x), 0x120 + (N), 0xf, 0xf, false))

// ---------------------------------------------------------------------------
// W1 prep only: W1 * adjacency -> bf16 workspace. 256 blocks x 256 = 65536
// float4 chunks exactly. (X conversion is fused into the main kernel.)
// ---------------------------------------------------------------------------
__global__ __launch_bounds__(256) void w1prep_kernel(
    const float* __restrict__ W1, const float* __restrict__ adj,
    unsigned short* __restrict__ W1bf)
{
    int c = blockIdx.x * 256 + threadIdx.x;   // 0..65535
    int flat = c * 4;
    int i = flat >> 12;        // node index
    int d = flat & 63;         // within-row offset (contiguous dim)
    float4 w = reinterpret_cast<const float4*>(W1)[c];
    float4 a = *reinterpret_cast<const float4*>(adj + i * DN + d);
    ushort4 o;
    o.x = f2bf(w.x * a.x); o.y = f2bf(w.y * a.y);
    o.z = f2bf(w.z * a.z); o.w = f2bf(w.w * a.w);
    reinterpret_cast<ushort4*>(W1bf)[c] = o;
}

// ---------------------------------------------------------------------------
// Main: block = (128-row batch tile, 4 nodes). 4 waves x 32 rows.
// X loaded fp32 + converted in-register (no Xbf round-trip). W1' staged in
// LDS (XOR-swizzled). j-loop fully unrolled: compiler hoists next-j ds_reads
// over current-j epilogue. Epilogue uses packed f32x2 fma + DPP reduction.
// btile-fastest block order: consecutive blocks share the 32 KB W1' tile.
// ---------------------------------------------------------------------------
__global__ __launch_bounds__(256, 3) void mlp_kernel(
    const float* __restrict__ X,               // [B][64] fp32
    const unsigned short* __restrict__ W1bf,   // [D][H][64] bf16 (adj folded)
    const float* __restrict__ W2,              // [D][H] fp32
    float* __restrict__ out)                   // [B][D] fp32
{
    const int btile = blockIdx.x & 127;        // fastest: W1'-tile L2 locality
    const int ng    = blockIdx.x >> 7;         // node group (4 nodes)
    const int wave  = threadIdx.x >> 6;        // 0..3
    const int lane  = threadIdx.x & 63;
    const int row16 = lane & 15;               // A/B frag row, C/D column (h)
    const int quad  = lane >> 4;               // A/B k-quad, C/D row-quad (b)

    __shared__ unsigned short ldsW1[4 * HN * DN];  // 32 KB, swizzled
    __shared__ float ldsW2[4 * HN];                // 1 KB
    __shared__ float lds_out[128][4];              // 2 KB

    // ---- A fragments: fp32 load + in-register bf16 convert ----
    const int b0 = btile * 128 + wave * 32;
    const float* aBase = X + (size_t)(b0 + row16) * DN + quad * 8;
    short8 afrag[2][2];
#pragma unroll
    for (int mt = 0; mt < 2; ++mt)
#pragma unroll
        for (int kk = 0; kk < 2; ++kk) {
            const float* p = aBase + mt * 16 * DN + kk * 32;
            float4 v0 = *reinterpret_cast<const float4*>(p);
            float4 v1 = *reinterpret_cast<const float4*>(p + 4);
            afrag[mt][kk] = cvt8(v0, v1);
        }

    // ---- Stage W1' (4 nodes = 2048 x 16B chunks) swizzled into LDS ----
    {
        const unsigned short* gsrc = W1bf + (size_t)ng * (4 * HN * DN);
#pragma unroll
        for (int it = 0; it < 8; ++it) {
            int chunk = it * 256 + threadIdx.x;      // 0..2047
            int nl = chunk >> 9;                     // node_local
            int rem = chunk & 511;
            int h = rem >> 3;
            int c = rem & 7;
            short8 v = *reinterpret_cast<const short8*>(gsrc + chunk * 8);
            int elem = nl * 4096 + h * 64 + ((c ^ (h & 7)) << 3);
            *reinterpret_cast<short8*>(&ldsW1[elem]) = v;
        }
        ldsW2[threadIdx.x] = W2[ng * 256 + threadIdx.x];
    }
    __syncthreads();

    // ---- j-loop: LDS-only operands, fully unrolled for cross-j overlap ----
#pragma unroll
    for (int j = 0; j < 4; ++j) {
        short8 bfrag[2][4];
#pragma unroll
        for (int kk = 0; kk < 2; ++kk)
#pragma unroll
            for (int nt = 0; nt < 4; ++nt) {
                int h = nt * 16 + row16;
                int elem = j * 4096 + h * 64 + (((kk * 4 + quad) ^ (row16 & 7)) << 3);
                bfrag[kk][nt] = *reinterpret_cast<const short8*>(&ldsW1[elem]);
            }

        float w2v[4];
#pragma unroll
        for (int nt = 0; nt < 4; ++nt)
            w2v[nt] = ldsW2[j * 64 + nt * 16 + row16];

        f32x4 acc[2][4];
#pragma unroll
        for (int mt = 0; mt < 2; ++mt)
#pragma unroll
            for (int nt = 0; nt < 4; ++nt)
                acc[mt][nt] = (f32x4){0.f, 0.f, 0.f, 0.f};

#pragma unroll
        for (int kk = 0; kk < 2; ++kk)
#pragma unroll
            for (int nt = 0; nt < 4; ++nt) {
                acc[0][nt] = __builtin_amdgcn_mfma_f32_16x16x32_bf16(afrag[0][kk], bfrag[kk][nt], acc[0][nt], 0, 0, 0);
                acc[1][nt] = __builtin_amdgcn_mfma_f32_16x16x32_bf16(afrag[1][kk], bfrag[kk][nt], acc[1][nt], 0, 0, 0);
            }

        // epilogue: out[b,node] = sum_h relu(H[b,h]) * W2[node,h]
        // C/D layout: h = nt*16 + row16, b = mt*16 + quad*4 + reg
#pragma unroll
        for (int mt = 0; mt < 2; ++mt) {
            f32x2 s01 = (f32x2){0.f, 0.f}, s23 = (f32x2){0.f, 0.f};
#pragma unroll
            for (int nt = 0; nt < 4; ++nt) {
                f32x2 m01 = (f32x2){fmaxf(acc[mt][nt][0], 0.f), fmaxf(acc[mt][nt][1], 0.f)};
                f32x2 m23 = (f32x2){fmaxf(acc[mt][nt][2], 0.f), fmaxf(acc[mt][nt][3], 0.f)};
                s01 += m01 * w2v[nt];     // v_pk_fma_f32
                s23 += m23 * w2v[nt];
            }
            float p[4] = {s01[0], s01[1], s23[0], s23[1]};
#pragma unroll
            for (int r = 0; r < 4; ++r) {
                DPP_ROR_ADD(p[r], 8);
                DPP_ROR_ADD(p[r], 4);
                DPP_ROR_ADD(p[r], 2);
                DPP_ROR_ADD(p[r], 1);
            }
            if (row16 < 4)
                lds_out[wave * 32 + mt * 16 + quad * 4 + row16][j] = p[row16];
        }
    }

    __syncthreads();
    // cooperative store: 128 rows; thread t stores row t's float4
    if (threadIdx.x < 128) {
        int row = threadIdx.x;
        float4 v = *reinterpret_cast<const float4*>(&lds_out[row][0]);
        *reinterpret_cast<float4*>(out + (size_t)(btile * 128 + row) * DN + ng * 4) = v;
    }
}

extern "C" void kernel_launch(void* const* d_in, const int* in_sizes, int n_in,
                              void* d_out, int out_size, void* d_ws, size_t ws_size,
                              hipStream_t stream) {
    const float* X   = (const float*)d_in[0];   // [B, D] fp32
    const float* adj = (const float*)d_in[1];   // [D, D] fp32
    const float* W1  = (const float*)d_in[2];   // [D, H, D] fp32
    const float* W2  = (const float*)d_in[3];   // [D, H] fp32
    float* out = (float*)d_out;                 // [B, D] fp32

    unsigned short* W1bf = (unsigned short*)d_ws;           // 512 KB

    w1prep_kernel<<<WCH / 256, 256, 0, stream>>>(W1, adj, W1bf);
    mlp_kernel<<<128 * 16, 256, 0, stream>>>(X, W1bf, W2, out);
}